// Round 2
// baseline (1237.252 us; speedup 1.0000x reference)
//
#include <hip/hip_runtime.h>

// bf16 handled as raw ushort (bf16 = top 16 bits of fp32).
typedef unsigned short bfu;

#define QKV_ELEMS 33554432ll   // per q/k/v matrix: 8 bl * 256 win * 8 head * 64 tok * 32 c
#define SCALE_F 0.17677669529663687f

__device__ __forceinline__ float b2f(bfu u) {
  return __uint_as_float(((unsigned int)u) << 16);
}
__device__ __forceinline__ bfu f2b(float f) {
  unsigned int u = __float_as_uint(f);
  u += 0x7fffu + ((u >> 16) & 1u);   // round-to-nearest-even
  return (bfu)(u >> 16);
}
__device__ __forceinline__ void cvt8(int4 v, float* f) {
  unsigned int w0 = (unsigned)v.x, w1 = (unsigned)v.y, w2 = (unsigned)v.z, w3 = (unsigned)v.w;
  f[0] = __uint_as_float(w0 << 16); f[1] = __uint_as_float(w0 & 0xffff0000u);
  f[2] = __uint_as_float(w1 << 16); f[3] = __uint_as_float(w1 & 0xffff0000u);
  f[4] = __uint_as_float(w2 << 16); f[5] = __uint_as_float(w2 & 0xffff0000u);
  f[6] = __uint_as_float(w3 << 16); f[7] = __uint_as_float(w3 & 0xffff0000u);
}

// Prep: transpose w_qkv [768][256] -> [256][768] f32, w_out [256][256] -> [256][256] f32,
// and gather the 64x64 relative-position bias table (f32).
__global__ void prep_kernel(const float* __restrict__ wq, const float* __restrict__ wo,
                            const float* __restrict__ pe, const int* __restrict__ rel,
                            float* __restrict__ wqT, float* __restrict__ woT,
                            float* __restrict__ bias)
{
  int t = blockIdx.x * 256 + threadIdx.x;
  if (t < 196608) { int n = t >> 8, k = t & 255; wqT[k * 768 + n] = wq[t]; }
  if (t < 65536)  { int n = t >> 8, k = t & 255; woT[k * 256 + n] = wo[t]; }
  if (t < 4096)   { int r0 = rel[2 * t], r1 = rel[2 * t + 1]; bias[t] = pe[r0 * 15 + r1]; }
}

// C[p][n] = sum_k A[p][k] * BT[k][n] + bias[n].
// A: [131072][256] row-major (MODE 0: f32 = x; MODE 1: bf16 = attn out).
// BT: [256][NCOLS] f32 (k-major).
// MODE 0: scatter to windowed bf16 qkv layout. MODE 1: dense f32 row-major out.
template<int NCOLS, int MODE>
__global__ __launch_bounds__(256)
void gemm_k256(const void* __restrict__ Av, const float* __restrict__ BT,
               const float* __restrict__ bias, void* __restrict__ outv)
{
  __shared__ float Xs[64][132];   // 64 rows x 128 k (fp32, padded)
  __shared__ float Bs[128][68];   // 128 k x 64 n (fp32, padded)
  const int bm = blockIdx.x, bn = blockIdx.y;
  const int t = threadIdx.x;
  const int tr4 = (t >> 4) << 2;
  const int tc4 = (t & 15) << 2;

  float acc[4][4] = {};

  for (int ph = 0; ph < 2; ++ph) {
    const int kb = ph << 7;
    if (MODE == 0) {
      const float* A = (const float*)Av;
      #pragma unroll
      for (int r = 0; r < 8; ++r) {
        int id = t + (r << 8);           // 0..2047
        int row = id >> 5, ko = (id & 31) << 2;
        float4 v = *(const float4*)(A + (size_t)(bm * 64 + row) * 256 + kb + ko);
        Xs[row][ko + 0] = v.x; Xs[row][ko + 1] = v.y;
        Xs[row][ko + 2] = v.z; Xs[row][ko + 3] = v.w;
      }
    } else {
      const bfu* A = (const bfu*)Av;
      #pragma unroll
      for (int r = 0; r < 4; ++r) {
        int id = t + (r << 8);
        int row = id >> 4, ko = (id & 15) << 3;
        int4 v = *(const int4*)(A + (size_t)(bm * 64 + row) * 256 + kb + ko);
        float f[8]; cvt8(v, f);
        #pragma unroll
        for (int e = 0; e < 8; ++e) Xs[row][ko + e] = f[e];
      }
    }
    #pragma unroll
    for (int r = 0; r < 8; ++r) {
      int id = t + (r << 8);             // 0..2047
      int k = id >> 4, no = (id & 15) << 2;
      float4 v = *(const float4*)(BT + (size_t)(kb + k) * NCOLS + bn * 64 + no);
      Bs[k][no + 0] = v.x; Bs[k][no + 1] = v.y;
      Bs[k][no + 2] = v.z; Bs[k][no + 3] = v.w;
    }
    __syncthreads();

    for (int kk = 0; kk < 128; kk += 4) {
      float a[4][4], b[4][4];
      #pragma unroll
      for (int i = 0; i < 4; ++i) {
        float4 v = *(const float4*)&Xs[tr4 + i][kk];
        a[i][0] = v.x; a[i][1] = v.y; a[i][2] = v.z; a[i][3] = v.w;
      }
      #pragma unroll
      for (int e = 0; e < 4; ++e) {
        float4 v = *(const float4*)&Bs[kk + e][tc4];
        b[e][0] = v.x; b[e][1] = v.y; b[e][2] = v.z; b[e][3] = v.w;
      }
      #pragma unroll
      for (int i = 0; i < 4; ++i)
        #pragma unroll
        for (int e = 0; e < 4; ++e)
          #pragma unroll
          for (int j = 0; j < 4; ++j)
            acc[i][j] = fmaf(a[i][e], b[e][j], acc[i][j]);
    }
    __syncthreads();
  }

  float bb[4];
  #pragma unroll
  for (int j = 0; j < 4; ++j) bb[j] = bias[bn * 64 + tc4 + j];

  #pragma unroll
  for (int i = 0; i < 4; ++i) {
    int p = bm * 64 + tr4 + i;
    if (MODE == 0) {
      bfu* out = (bfu*)outv;
      ushort4 u;
      u.x = f2b(acc[i][0] + bb[0]);
      u.y = f2b(acc[i][1] + bb[1]);
      u.z = f2b(acc[i][2] + bb[2]);
      u.w = f2b(acc[i][3] + bb[3]);
      int bl = p >> 14, rem = p & 16383;
      int y = rem >> 7, x = rem & 127;
      int win = ((y >> 3) << 4) | (x >> 3);
      int tok = ((y & 7) << 3) | (x & 7);
      int col = bn * 64 + tc4;
      int m = col >> 8, r2 = col & 255;
      int head = r2 >> 5, cc = r2 & 31;
      size_t dst = (size_t)m * QKV_ELEMS
                 + ((((size_t)bl * 256 + win) * 8 + head) * 64 + tok) * 32 + cc;
      *(ushort4*)(out + dst) = u;
    } else {
      float* out = (float*)outv;
      float4 v;
      v.x = acc[i][0] + bb[0]; v.y = acc[i][1] + bb[1];
      v.z = acc[i][2] + bb[2]; v.w = acc[i][3] + bb[3];
      *(float4*)(out + (size_t)p * 256 + bn * 64 + tc4) = v;
    }
  }
}

// One 64-thread block per (bl, win, head). Thread t owns query row t.
__global__ __launch_bounds__(64)
void attn_kernel(const bfu* __restrict__ qkv, const float* __restrict__ bias,
                 bfu* __restrict__ aout)
{
  __shared__ float Ks[64][36];
  __shared__ float Vs[64][36];
  const int blk = blockIdx.x;          // (bl*256 + win)*8 + head
  const int head = blk & 7;
  const int blwin = blk >> 3;
  const int win = blwin & 255;
  const int bl = blwin >> 8;
  const int t = threadIdx.x;

  const bfu* qb = qkv + (size_t)blk * 2048;
  const bfu* kb = qb + QKV_ELEMS;
  const bfu* vb = qb + 2 * QKV_ELEMS;

  float q[32];
  #pragma unroll
  for (int c = 0; c < 32; c += 8) {
    int4 v = *(const int4*)(qb + t * 32 + c);
    float f[8]; cvt8(v, f);
    #pragma unroll
    for (int e = 0; e < 8; ++e) q[c + e] = f[e];
  }
  #pragma unroll
  for (int c = 0; c < 32; c += 8) {
    int4 v = *(const int4*)(kb + t * 32 + c);
    float f[8]; cvt8(v, f);
    #pragma unroll
    for (int e = 0; e < 8; ++e) Ks[t][c + e] = f[e];
    v = *(const int4*)(vb + t * 32 + c);
    cvt8(v, f);
    #pragma unroll
    for (int e = 0; e < 8; ++e) Vs[t][c + e] = f[e];
  }
  __syncthreads();

  float s[64];
  const float* brow = bias + t * 64;
  #pragma unroll
  for (int j = 0; j < 64; ++j) {
    float d = 0.f;
    #pragma unroll
    for (int c = 0; c < 32; ++c) d = fmaf(q[c], Ks[j][c], d);
    s[j] = d * SCALE_F + brow[j];
  }
  float mx = s[0];
  #pragma unroll
  for (int j = 1; j < 64; ++j) mx = fmaxf(mx, s[j]);
  float sum = 0.f;
  #pragma unroll
  for (int j = 0; j < 64; ++j) { s[j] = __expf(s[j] - mx); sum += s[j]; }
  float inv = 1.f / sum;

  float o[32] = {};
  #pragma unroll
  for (int j = 0; j < 64; ++j) {
    float pj = s[j];
    #pragma unroll
    for (int c = 0; c < 32; ++c) o[c] = fmaf(pj, Vs[j][c], o[c]);
  }

  int y = ((win >> 4) << 3) | (t >> 3);
  int x = ((win & 15) << 3) | (t & 7);
  size_t p = ((size_t)bl * 128 + y) * 128 + x;
  bfu* dst = aout + p * 256 + head * 32;
  #pragma unroll
  for (int c = 0; c < 32; c += 4) {
    ushort4 u;
    u.x = f2b(o[c + 0] * inv); u.y = f2b(o[c + 1] * inv);
    u.z = f2b(o[c + 2] * inv); u.w = f2b(o[c + 3] * inv);
    *(ushort4*)(dst + c) = u;
  }
}

extern "C" void kernel_launch(void* const* d_in, const int* in_sizes, int n_in,
                              void* d_out, int out_size, void* d_ws, size_t ws_size,
                              hipStream_t stream)
{
  const float* x     = (const float*)d_in[0];
  const float* w_qkv = (const float*)d_in[1];
  const float* b_qkv = (const float*)d_in[2];
  const float* w_out = (const float*)d_in[3];
  const float* b_out = (const float*)d_in[4];
  const float* pe    = (const float*)d_in[5];
  const int*   rel   = (const int*)d_in[6];
  float* out = (float*)d_out;

  char* ws = (char*)d_ws;
  bfu*   qkv_ws  = (bfu*)(ws);                 // 3 * 33554432 bf16 = 192 MiB
  bfu*   attn_ws = (bfu*)(ws + 201326592);     // 33554432 bf16 = 64 MiB
  float* bias_ws = (float*)(ws + 268435456);   // 4096 f32
  float* wqkvT   = (float*)(ws + 268451840);   // 196608 f32
  float* woutT   = (float*)(ws + 269238272);   // 65536 f32

  prep_kernel<<<768, 256, 0, stream>>>(w_qkv, w_out, pe, rel, wqkvT, woutT, bias_ws);
  gemm_k256<768, 0><<<dim3(2048, 12), 256, 0, stream>>>(x, wqkvT, b_qkv, qkv_ws);
  attn_kernel<<<16384, 64, 0, stream>>>(qkv_ws, bias_ws, attn_ws);
  gemm_k256<256, 1><<<dim3(2048, 4), 256, 0, stream>>>(attn_ws, woutT, b_out, out);
}

// Round 3
// 497.548 us; speedup vs baseline: 2.4867x; 2.4867x over previous
//
#include <hip/hip_runtime.h>

// bf16 handled as raw ushort (bf16 = top 16 bits of fp32).
typedef unsigned short bfu;
typedef __attribute__((ext_vector_type(8))) short bf16x8;   // 8 bf16 = 4 VGPRs
typedef __attribute__((ext_vector_type(4))) float f32x4;

#define QKV_ELEMS 33554432ll   // per q/k/v matrix: 8 bl * 256 win * 8 head * 64 tok * 32 c
#define SCALE_F 0.17677669529663687f

__device__ __forceinline__ float b2f(bfu u) {
  return __uint_as_float(((unsigned int)u) << 16);
}
__device__ __forceinline__ bfu f2b(float f) {
  unsigned int u = __float_as_uint(f);
  u += 0x7fffu + ((u >> 16) & 1u);   // round-to-nearest-even
  return (bfu)(u >> 16);
}
__device__ __forceinline__ unsigned pk2(float a, float b) {
  return ((unsigned)f2b(b) << 16) | (unsigned)f2b(a);
}
__device__ __forceinline__ void cvt8(int4 v, float* f) {
  unsigned int w0 = (unsigned)v.x, w1 = (unsigned)v.y, w2 = (unsigned)v.z, w3 = (unsigned)v.w;
  f[0] = __uint_as_float(w0 << 16); f[1] = __uint_as_float(w0 & 0xffff0000u);
  f[2] = __uint_as_float(w1 << 16); f[3] = __uint_as_float(w1 & 0xffff0000u);
  f[4] = __uint_as_float(w2 << 16); f[5] = __uint_as_float(w2 & 0xffff0000u);
  f[6] = __uint_as_float(w3 << 16); f[7] = __uint_as_float(w3 & 0xffff0000u);
}

// Prep: cvt w_qkv [768][256] f32 -> bf16 (same layout = N x K), w_out [256][256]
// likewise, and gather the 64x64 relative-position bias table (f32).
__global__ void prep_kernel(const float* __restrict__ wq, const float* __restrict__ wo,
                            const float* __restrict__ pe, const int* __restrict__ rel,
                            bfu* __restrict__ wqB, bfu* __restrict__ woB,
                            float* __restrict__ bias)
{
  int t = blockIdx.x * 256 + threadIdx.x;
  if (t < 196608) wqB[t] = f2b(wq[t]);
  if (t < 65536)  woB[t] = f2b(wo[t]);
  if (t < 4096)   { int r0 = rel[2 * t], r1 = rel[2 * t + 1]; bias[t] = pe[r0 * 15 + r1]; }
}

// C[m][n] = sum_k A[m][k]*B[n][k] + bias[n].   M=131072, K=256, N=NBN*128.
// A: [M][256] row-major (MODE 0: f32; MODE 1: bf16). B: [N][256] bf16 row-major.
// MODE 0: scatter bf16 to windowed qkv layout. MODE 1: dense f32 row-major out.
// 256 thr = 4 waves in 2x2; wave = 64x64 quadrant = 4x4 frags of 16x16 (mfma 16x16x32 bf16).
// LDS: As[128 m][64 k] + Bs[128 n][64 k] bf16, 16B-unit XOR swizzle (u ^= row&7).
template<int NBN, int MODE>
__global__ __launch_bounds__(256)
void mfma_gemm(const void* __restrict__ Av, const bfu* __restrict__ B,
               const float* __restrict__ bias, void* __restrict__ outv)
{
  __shared__ char lds[65536];
  const int t = threadIdx.x;
  const int lane = t & 63;
  const int l15 = lane & 15, l4 = lane >> 4;
  const int wid = t >> 6;
  const int wr = wid >> 1, wc = wid & 1;

  // XCD-chunked remap: consecutive work-ids (sharing an A panel) stay on one XCD's L2.
  const int L = blockIdx.x;
  const int chunk = (NBN * 1024) >> 3;
  const int w = (L & 7) * chunk + (L >> 3);
  const int bm = w / NBN, bn = w % NBN;

  f32x4 acc[4][4] = {};

  for (int kt = 0; kt < 4; ++kt) {
    #pragma unroll
    for (int r = 0; r < 4; ++r) {
      int slot = t + (r << 8);           // 0..1023
      int row = slot >> 3, u = slot & 7;
      int su = (u ^ (row & 7)) << 4;
      if (MODE == 0) {
        const float* p = (const float*)Av + (((size_t)(bm * 128 + row)) << 8) + (kt << 6) + (u << 3);
        float4 lo = *(const float4*)p;
        float4 hi = *(const float4*)(p + 4);
        int4 pk;
        pk.x = pk2(lo.x, lo.y); pk.y = pk2(lo.z, lo.w);
        pk.z = pk2(hi.x, hi.y); pk.w = pk2(hi.z, hi.w);
        *(int4*)(lds + (row << 7) + su) = pk;
      } else {
        const bfu* p = (const bfu*)Av + (((size_t)(bm * 128 + row)) << 8) + (kt << 6) + (u << 3);
        *(int4*)(lds + (row << 7) + su) = *(const int4*)p;
      }
      const bfu* pb = B + (((size_t)(bn * 128 + row)) << 8) + (kt << 6) + (u << 3);
      *(int4*)(lds + 32768 + (row << 7) + su) = *(const int4*)pb;
    }
    __syncthreads();

    #pragma unroll
    for (int kk = 0; kk < 2; ++kk) {
      bf16x8 af[4], bfr[4];
      #pragma unroll
      for (int ms = 0; ms < 4; ++ms) {
        int row = (wr << 6) + (ms << 4) + l15;
        int u = (((kk << 2) + l4) ^ (row & 7)) << 4;
        af[ms] = *(const bf16x8*)(lds + (row << 7) + u);
      }
      #pragma unroll
      for (int ns = 0; ns < 4; ++ns) {
        int row = (wc << 6) + (ns << 4) + l15;
        int u = (((kk << 2) + l4) ^ (row & 7)) << 4;
        bfr[ns] = *(const bf16x8*)(lds + 32768 + (row << 7) + u);
      }
      #pragma unroll
      for (int ms = 0; ms < 4; ++ms)
        #pragma unroll
        for (int ns = 0; ns < 4; ++ns)
          acc[ms][ns] = __builtin_amdgcn_mfma_f32_16x16x32_bf16(af[ms], bfr[ns], acc[ms][ns], 0, 0, 0);
    }
    __syncthreads();
  }

  // Epilogue. D[(l>>4)*4 + r][lane&15] = acc[..][r]  (HW-verified C/D mapping).
  if (MODE == 0) {
    bfu* out = (bfu*)outv;
    #pragma unroll
    for (int ns = 0; ns < 4; ++ns) {
      int n = bn * 128 + (wc << 6) + (ns << 4) + l15;
      float bb = bias[n];
      int mat = n >> 8, head = (n >> 5) & 7, cc = n & 31;
      size_t nbase = (size_t)mat * QKV_ELEMS + head * 2048 + cc;
      #pragma unroll
      for (int ms = 0; ms < 4; ++ms) {
        int m = bm * 128 + (wr << 6) + (ms << 4) + (l4 << 2);
        int bl = m >> 14, y = (m >> 7) & 127, x = m & 127;
        int win = ((y >> 3) << 4) | (x >> 3);
        int tok = ((y & 7) << 3) | (x & 7);   // 4-aligned; r spans tok..tok+3
        size_t tb = nbase + (size_t)(bl * 256 + win) * 16384 + tok * 32;
        #pragma unroll
        for (int r = 0; r < 4; ++r)
          out[tb + (size_t)r * 32] = f2b(acc[ms][ns][r] + bb);
      }
    }
  } else {
    float* out = (float*)outv;
    #pragma unroll
    for (int ns = 0; ns < 4; ++ns) {
      int n = bn * 128 + (wc << 6) + (ns << 4) + l15;
      float bb = bias[n];
      #pragma unroll
      for (int ms = 0; ms < 4; ++ms) {
        int m = bm * 128 + (wr << 6) + (ms << 4) + (l4 << 2);
        #pragma unroll
        for (int r = 0; r < 4; ++r)
          out[((size_t)(m + r) << 8) + n] = acc[ms][ns][r] + bb;
      }
    }
  }
}

// One 64-thread block per (bl, win, head). Thread t owns query row t.
__global__ __launch_bounds__(64)
void attn_kernel(const bfu* __restrict__ qkv, const float* __restrict__ bias,
                 bfu* __restrict__ aout)
{
  __shared__ float Ks[64][36];
  __shared__ float Vs[64][36];
  const int blk = blockIdx.x;          // (bl*256 + win)*8 + head
  const int head = blk & 7;
  const int blwin = blk >> 3;
  const int win = blwin & 255;
  const int bl = blwin >> 8;
  const int t = threadIdx.x;

  const bfu* qb = qkv + (size_t)blk * 2048;
  const bfu* kb = qb + QKV_ELEMS;
  const bfu* vb = qb + 2 * QKV_ELEMS;

  float q[32];
  #pragma unroll
  for (int c = 0; c < 32; c += 8) {
    int4 v = *(const int4*)(qb + t * 32 + c);
    float f[8]; cvt8(v, f);
    #pragma unroll
    for (int e = 0; e < 8; ++e) q[c + e] = f[e];
  }
  #pragma unroll
  for (int c = 0; c < 32; c += 8) {
    int4 v = *(const int4*)(kb + t * 32 + c);
    float f[8]; cvt8(v, f);
    #pragma unroll
    for (int e = 0; e < 8; ++e) Ks[t][c + e] = f[e];
    v = *(const int4*)(vb + t * 32 + c);
    cvt8(v, f);
    #pragma unroll
    for (int e = 0; e < 8; ++e) Vs[t][c + e] = f[e];
  }
  __syncthreads();

  float s[64];
  const float* brow = bias + t * 64;
  #pragma unroll
  for (int j = 0; j < 64; ++j) {
    float d = 0.f;
    #pragma unroll
    for (int c = 0; c < 32; ++c) d = fmaf(q[c], Ks[j][c], d);
    s[j] = d * SCALE_F + brow[j];
  }
  float mx = s[0];
  #pragma unroll
  for (int j = 1; j < 64; ++j) mx = fmaxf(mx, s[j]);
  float sum = 0.f;
  #pragma unroll
  for (int j = 0; j < 64; ++j) { s[j] = __expf(s[j] - mx); sum += s[j]; }
  float inv = 1.f / sum;

  float o[32] = {};
  #pragma unroll
  for (int j = 0; j < 64; ++j) {
    float pj = s[j];
    #pragma unroll
    for (int c = 0; c < 32; ++c) o[c] = fmaf(pj, Vs[j][c], o[c]);
  }

  int y = ((win >> 4) << 3) | (t >> 3);
  int x = ((win & 15) << 3) | (t & 7);
  size_t p = ((size_t)bl * 128 + y) * 128 + x;
  bfu* dst = aout + p * 256 + head * 32;
  #pragma unroll
  for (int c = 0; c < 32; c += 4) {
    ushort4 u;
    u.x = f2b(o[c + 0] * inv); u.y = f2b(o[c + 1] * inv);
    u.z = f2b(o[c + 2] * inv); u.w = f2b(o[c + 3] * inv);
    *(ushort4*)(dst + c) = u;
  }
}

extern "C" void kernel_launch(void* const* d_in, const int* in_sizes, int n_in,
                              void* d_out, int out_size, void* d_ws, size_t ws_size,
                              hipStream_t stream)
{
  const float* x     = (const float*)d_in[0];
  const float* w_qkv = (const float*)d_in[1];
  const float* b_qkv = (const float*)d_in[2];
  const float* w_out = (const float*)d_in[3];
  const float* b_out = (const float*)d_in[4];
  const float* pe    = (const float*)d_in[5];
  const int*   rel   = (const int*)d_in[6];
  float* out = (float*)d_out;

  char* ws = (char*)d_ws;
  bfu*   qkv_ws  = (bfu*)(ws);                 // 3 * 33554432 bf16 = 192 MiB
  bfu*   attn_ws = (bfu*)(ws + 201326592);     // 33554432 bf16 = 64 MiB (dense [131072][256])
  float* bias_ws = (float*)(ws + 268435456);   // 4096 f32
  bfu*   wqB     = (bfu*)(ws + 268451840);     // 196608 bf16 [768][256] (N x K)
  bfu*   woB     = (bfu*)(ws + 268845056);     // 65536 bf16 [256][256] (N x K)

  prep_kernel<<<768, 256, 0, stream>>>(w_qkv, w_out, pe, rel, wqB, woB, bias_ws);
  mfma_gemm<6, 0><<<6144, 256, 0, stream>>>(x, wqB, b_qkv, qkv_ws);
  attn_kernel<<<16384, 64, 0, stream>>>(qkv_ws, bias_ws, attn_ws);
  mfma_gemm<2, 1><<<2048, 256, 0, stream>>>(attn_ws, woB, b_out, out);
}

// Round 4
// 308.636 us; speedup vs baseline: 4.0088x; 1.6121x over previous
//
#include <hip/hip_runtime.h>

// bf16 handled as raw ushort (bf16 = top 16 bits of fp32).
typedef unsigned short bfu;
typedef __attribute__((ext_vector_type(8))) short bf16x8;   // 8 bf16 = 4 VGPRs
typedef __attribute__((ext_vector_type(4))) float f32x4;

#define QKV_ELEMS 33554432ll   // per q/k/v matrix: 8 bl * 256 win * 8 head * 64 tok * 32 c
#define SCALE_F 0.17677669529663687f

__device__ __forceinline__ bfu f2b(float f) {
  unsigned int u = __float_as_uint(f);
  u += 0x7fffu + ((u >> 16) & 1u);   // round-to-nearest-even
  return (bfu)(u >> 16);
}
__device__ __forceinline__ unsigned pk2(float a, float b) {
  return ((unsigned)f2b(b) << 16) | (unsigned)f2b(a);
}

// Prep: cvt w_qkv [768][256] f32 -> bf16 (N x K), w_out [256][256] likewise,
// and gather the 64x64 relative-position bias table (f32).
__global__ void prep_kernel(const float* __restrict__ wq, const float* __restrict__ wo,
                            const float* __restrict__ pe, const int* __restrict__ rel,
                            bfu* __restrict__ wqB, bfu* __restrict__ woB,
                            float* __restrict__ bias)
{
  int t = blockIdx.x * 256 + threadIdx.x;
  if (t < 196608) wqB[t] = f2b(wq[t]);
  if (t < 65536)  woB[t] = f2b(wo[t]);
  if (t < 4096)   { int r0 = rel[2 * t], r1 = rel[2 * t + 1]; bias[t] = pe[r0 * 15 + r1]; }
}

// C[m][n] = sum_k A[m][k]*B[n][k] + bias[n].   M=131072, K=256, N=NBN*128.
// A: [M][256] row-major (MODE 0: f32; MODE 1: bf16). B: [N][256] bf16 row-major.
// MODE 0: scatter bf16 to windowed qkv layout (Q,K as [tok][c]; V transposed [c][tok]).
// MODE 1: dense f32 row-major out.
template<int NBN, int MODE>
__global__ __launch_bounds__(256)
void mfma_gemm(const void* __restrict__ Av, const bfu* __restrict__ B,
               const float* __restrict__ bias, void* __restrict__ outv)
{
  __shared__ char lds[65536];
  const int t = threadIdx.x;
  const int lane = t & 63;
  const int l15 = lane & 15, l4 = lane >> 4;
  const int wid = t >> 6;
  const int wr = wid >> 1, wc = wid & 1;

  // XCD-chunked remap: consecutive work-ids (sharing an A panel) stay on one XCD's L2.
  const int L = blockIdx.x;
  const int chunk = (NBN * 1024) >> 3;
  const int w = (L & 7) * chunk + (L >> 3);
  const int bm = w / NBN, bn = w % NBN;

  f32x4 acc[4][4] = {};

  for (int kt = 0; kt < 4; ++kt) {
    #pragma unroll
    for (int r = 0; r < 4; ++r) {
      int slot = t + (r << 8);           // 0..1023
      int row = slot >> 3, u = slot & 7;
      int su = (u ^ (row & 7)) << 4;
      if (MODE == 0) {
        const float* p = (const float*)Av + (((size_t)(bm * 128 + row)) << 8) + (kt << 6) + (u << 3);
        float4 lo = *(const float4*)p;
        float4 hi = *(const float4*)(p + 4);
        int4 pk;
        pk.x = pk2(lo.x, lo.y); pk.y = pk2(lo.z, lo.w);
        pk.z = pk2(hi.x, hi.y); pk.w = pk2(hi.z, hi.w);
        *(int4*)(lds + (row << 7) + su) = pk;
      } else {
        const bfu* p = (const bfu*)Av + (((size_t)(bm * 128 + row)) << 8) + (kt << 6) + (u << 3);
        *(int4*)(lds + (row << 7) + su) = *(const int4*)p;
      }
      const bfu* pb = B + (((size_t)(bn * 128 + row)) << 8) + (kt << 6) + (u << 3);
      *(int4*)(lds + 32768 + (row << 7) + su) = *(const int4*)pb;
    }
    __syncthreads();

    #pragma unroll
    for (int kk = 0; kk < 2; ++kk) {
      bf16x8 af[4], bfr[4];
      #pragma unroll
      for (int ms = 0; ms < 4; ++ms) {
        int row = (wr << 6) + (ms << 4) + l15;
        int u = (((kk << 2) + l4) ^ (row & 7)) << 4;
        af[ms] = *(const bf16x8*)(lds + (row << 7) + u);
      }
      #pragma unroll
      for (int ns = 0; ns < 4; ++ns) {
        int row = (wc << 6) + (ns << 4) + l15;
        int u = (((kk << 2) + l4) ^ (row & 7)) << 4;
        bfr[ns] = *(const bf16x8*)(lds + 32768 + (row << 7) + u);
      }
      #pragma unroll
      for (int ms = 0; ms < 4; ++ms)
        #pragma unroll
        for (int ns = 0; ns < 4; ++ns)
          acc[ms][ns] = __builtin_amdgcn_mfma_f32_16x16x32_bf16(af[ms], bfr[ns], acc[ms][ns], 0, 0, 0);
    }
    __syncthreads();
  }

  // Epilogue. D[(l>>4)*4 + r][lane&15] = acc[..][r]  (HW-verified C/D mapping).
  if (MODE == 0) {
    bfu* out = (bfu*)outv;
    #pragma unroll
    for (int ns = 0; ns < 4; ++ns) {
      int n = bn * 128 + (wc << 6) + (ns << 4) + l15;
      float bb = bias[n];
      int mat = n >> 8, head = (n >> 5) & 7, cc = n & 31;
      #pragma unroll
      for (int ms = 0; ms < 4; ++ms) {
        int m = bm * 128 + (wr << 6) + (ms << 4) + (l4 << 2);
        int bl = m >> 14, y = (m >> 7) & 127, x = m & 127;
        int win = ((y >> 3) << 4) | (x >> 3);
        int tok = ((y & 7) << 3) | (x & 7);   // 4-aligned; r spans tok..tok+3
        if (mat == 2) {
          // V^T layout: [bl,win,head][c=32][tok=64], contiguous in tok.
          size_t tb = 2 * QKV_ELEMS + ((size_t)(bl * 256 + win) * 8 + head) * 2048
                    + (size_t)cc * 64 + tok;
          ushort4 u4;
          u4.x = f2b(acc[ms][ns][0] + bb);
          u4.y = f2b(acc[ms][ns][1] + bb);
          u4.z = f2b(acc[ms][ns][2] + bb);
          u4.w = f2b(acc[ms][ns][3] + bb);
          *(ushort4*)(out + tb) = u4;
        } else {
          size_t tb = (size_t)mat * QKV_ELEMS + ((size_t)(bl * 256 + win) * 8 + head) * 2048
                    + (size_t)tok * 32 + cc;
          #pragma unroll
          for (int r = 0; r < 4; ++r)
            out[tb + (size_t)r * 32] = f2b(acc[ms][ns][r] + bb);
        }
      }
    }
  } else {
    float* out = (float*)outv;
    #pragma unroll
    for (int ns = 0; ns < 4; ++ns) {
      int n = bn * 128 + (wc << 6) + (ns << 4) + l15;
      float bb = bias[n];
      #pragma unroll
      for (int ms = 0; ms < 4; ++ms) {
        int m = bm * 128 + (wr << 6) + (ms << 4) + (l4 << 2);
        #pragma unroll
        for (int r = 0; r < 4; ++r)
          out[((size_t)(m + r) << 8) + n] = acc[ms][ns][r] + bb;
      }
    }
  }
}

// MFMA window attention. One block per (bl, win); 4 waves x 2 heads each.
// Swapped QK^T (S^T = mfma(K, Q)) so each lane owns whole q-rows for softmax.
// P staged per-wave in XOR-swizzled LDS; V read pre-transposed from global.
__global__ __launch_bounds__(256)
void attn_mfma(const bfu* __restrict__ qkv, const float* __restrict__ bias,
               bfu* __restrict__ aout)
{
  __shared__ float bias_s[64 * 68];   // padded: stride 68 f32
  __shared__ bfu p_s[4][4096];        // per-wave swizzled [64][64] bf16
  __shared__ float inv_s[4][64];
  const int t = threadIdx.x;
  const int lane = t & 63, wid = t >> 6;
  const int l15 = lane & 15, l4 = lane >> 4;
  const int blwin = blockIdx.x;       // bl*256 + win
  const int bl = blwin >> 8, win = blwin & 255;

  {
    int idx = t << 4;
    int i = idx >> 6, j0 = idx & 63;
    #pragma unroll
    for (int e = 0; e < 4; ++e) {
      float4 v = *(const float4*)(bias + idx + e * 4);
      *(float4*)(bias_s + i * 68 + j0 + e * 4) = v;
    }
  }
  __syncthreads();

  char* ps = (char*)&p_s[wid][0];

  #pragma unroll 1
  for (int hh = 0; hh < 2; ++hh) {
    const int head = wid * 2 + hh;
    const bfu* qb  = qkv + ((size_t)blwin * 8 + head) * 2048;
    const bfu* kb  = qb + QKV_ELEMS;
    const bfu* vtb = qb + 2 * QKV_ELEMS;   // [32 c][64 tok]

    bf16x8 qf[4], kf[4], vf[2][2];
    #pragma unroll
    for (int i = 0; i < 4; ++i) {
      qf[i] = *(const bf16x8*)(qb + (i * 16 + l15) * 32 + l4 * 8);
      kf[i] = *(const bf16x8*)(kb + (i * 16 + l15) * 32 + l4 * 8);
    }
    #pragma unroll
    for (int nj = 0; nj < 2; ++nj)
      #pragma unroll
      for (int ks = 0; ks < 2; ++ks)
        vf[nj][ks] = *(const bf16x8*)(vtb + (nj * 16 + l15) * 64 + ks * 32 + l4 * 8);

    // S^T[j][i]: reg r -> j = mj*16 + l4*4 + r; col -> i = ni*16 + l15.
    f32x4 st[4][4] = {};   // [mj][ni]
    #pragma unroll
    for (int mj = 0; mj < 4; ++mj)
      #pragma unroll
      for (int ni = 0; ni < 4; ++ni)
        st[mj][ni] = __builtin_amdgcn_mfma_f32_16x16x32_bf16(kf[mj], qf[ni], st[mj][ni], 0, 0, 0);

    // scale + bias
    #pragma unroll
    for (int ni = 0; ni < 4; ++ni) {
      int i = ni * 16 + l15;
      #pragma unroll
      for (int mj = 0; mj < 4; ++mj) {
        float4 bb = *(const float4*)(bias_s + i * 68 + mj * 16 + l4 * 4);
        st[mj][ni][0] = fmaf(st[mj][ni][0], SCALE_F, bb.x);
        st[mj][ni][1] = fmaf(st[mj][ni][1], SCALE_F, bb.y);
        st[mj][ni][2] = fmaf(st[mj][ni][2], SCALE_F, bb.z);
        st[mj][ni][3] = fmaf(st[mj][ni][3], SCALE_F, bb.w);
      }
    }

    // softmax over j for each owned q-row; write unnormalized P to swizzled LDS.
    #pragma unroll
    for (int ni = 0; ni < 4; ++ni) {
      float mx = st[0][ni][0];
      #pragma unroll
      for (int mj = 0; mj < 4; ++mj)
        #pragma unroll
        for (int r = 0; r < 4; ++r)
          mx = fmaxf(mx, st[mj][ni][r]);
      mx = fmaxf(mx, __shfl_xor(mx, 16));
      mx = fmaxf(mx, __shfl_xor(mx, 32));
      float sum = 0.f;
      #pragma unroll
      for (int mj = 0; mj < 4; ++mj)
        #pragma unroll
        for (int r = 0; r < 4; ++r) {
          float p = __expf(st[mj][ni][r] - mx);
          st[mj][ni][r] = p;
          sum += p;
        }
      sum += __shfl_xor(sum, 16);
      sum += __shfl_xor(sum, 32);
      if (l4 == 0) inv_s[wid][ni * 16 + l15] = 1.0f / sum;
      const int i2 = ni * 16 + l15;
      const int swz = (i2 & 7) << 4;
      #pragma unroll
      for (int mj = 0; mj < 4; ++mj) {
        uint2 val;
        val.x = pk2(st[mj][ni][0], st[mj][ni][1]);
        val.y = pk2(st[mj][ni][2], st[mj][ni][3]);
        *(uint2*)(ps + i2 * 128 + ((mj * 32 + l4 * 8) ^ swz)) = val;
      }
    }

    // PV: O[i][c] = sum_j P[i][j] * Vt[c][j]
    f32x4 oacc[4][2] = {};
    #pragma unroll
    for (int mi = 0; mi < 4; ++mi) {
      int i = mi * 16 + l15;
      int swz = (i & 7) << 4;
      bf16x8 pf0 = *(const bf16x8*)(ps + i * 128 + ((l4 * 16) ^ swz));
      bf16x8 pf1 = *(const bf16x8*)(ps + i * 128 + ((64 + l4 * 16) ^ swz));
      #pragma unroll
      for (int nj = 0; nj < 2; ++nj) {
        oacc[mi][nj] = __builtin_amdgcn_mfma_f32_16x16x32_bf16(pf0, vf[nj][0], oacc[mi][nj], 0, 0, 0);
        oacc[mi][nj] = __builtin_amdgcn_mfma_f32_16x16x32_bf16(pf1, vf[nj][1], oacc[mi][nj], 0, 0, 0);
      }
    }

    // epilogue: row i = mi*16 + l4*4 + r, col c = nj*16 + l15
    #pragma unroll
    for (int mi = 0; mi < 4; ++mi) {
      #pragma unroll
      for (int r = 0; r < 4; ++r) {
        int tok = mi * 16 + (l4 << 2) + r;
        float inv = inv_s[wid][tok];
        int y = ((win >> 4) << 3) | (tok >> 3);
        int x = ((win & 15) << 3) | (tok & 7);
        size_t p = ((size_t)bl * 128 + y) * 128 + x;
        bfu* dst = aout + p * 256 + head * 32;
        #pragma unroll
        for (int nj = 0; nj < 2; ++nj)
          dst[nj * 16 + l15] = f2b(oacc[mi][nj][r] * inv);
      }
    }
  }
}

extern "C" void kernel_launch(void* const* d_in, const int* in_sizes, int n_in,
                              void* d_out, int out_size, void* d_ws, size_t ws_size,
                              hipStream_t stream)
{
  const float* x     = (const float*)d_in[0];
  const float* w_qkv = (const float*)d_in[1];
  const float* b_qkv = (const float*)d_in[2];
  const float* w_out = (const float*)d_in[3];
  const float* b_out = (const float*)d_in[4];
  const float* pe    = (const float*)d_in[5];
  const int*   rel   = (const int*)d_in[6];
  float* out = (float*)d_out;

  char* ws = (char*)d_ws;
  bfu*   qkv_ws  = (bfu*)(ws);                 // 3 * 33554432 bf16 = 192 MiB
  bfu*   attn_ws = (bfu*)(ws + 201326592);     // 33554432 bf16 = 64 MiB (dense [131072][256])
  float* bias_ws = (float*)(ws + 268435456);   // 4096 f32
  bfu*   wqB     = (bfu*)(ws + 268451840);     // 196608 bf16 [768][256] (N x K)
  bfu*   woB     = (bfu*)(ws + 268845056);     // 65536 bf16 [256][256] (N x K)

  prep_kernel<<<768, 256, 0, stream>>>(w_qkv, w_out, pe, rel, wqB, woB, bias_ws);
  mfma_gemm<6, 0><<<6144, 256, 0, stream>>>(x, wqB, b_qkv, qkv_ws);
  attn_mfma<<<2048, 256, 0, stream>>>(qkv_ws, bias_ws, attn_ws);
  mfma_gemm<2, 1><<<2048, 256, 0, stream>>>(attn_ws, woB, b_out, out);
}

// Round 6
// 262.016 us; speedup vs baseline: 4.7220x; 1.1779x over previous
//
#include <hip/hip_runtime.h>

// bf16 handled as raw ushort (bf16 = top 16 bits of fp32).
typedef unsigned short bfu;
typedef unsigned int u32;
typedef __attribute__((ext_vector_type(8))) short bf16x8;   // 8 bf16 = 4 VGPRs
typedef __attribute__((ext_vector_type(4))) float f32x4;

#define QKV_ELEMS 33554432ll   // per q/k/v matrix: 8 bl * 256 win * 8 head * 64 tok * 32 c
#define SCALE_F 0.17677669529663687f

__device__ __forceinline__ bfu f2b(float f) {
  unsigned int u = __float_as_uint(f);
  u += 0x7fffu + ((u >> 16) & 1u);   // round-to-nearest-even
  return (bfu)(u >> 16);
}
__device__ __forceinline__ unsigned pk2(float a, float b) {
  return ((unsigned)f2b(b) << 16) | (unsigned)f2b(a);
}
__device__ __forceinline__ void gload_lds16(const void* g, void* l) {
  __builtin_amdgcn_global_load_lds(
      (const __attribute__((address_space(1))) u32*)g,
      (__attribute__((address_space(3))) u32*)l, 16, 0, 0);
}

// x f32 [33554432] -> bf16 (round-to-nearest-even).
__global__ __launch_bounds__(256)
void cvt_x(const float* __restrict__ x, bfu* __restrict__ xb)
{
  size_t i = ((size_t)blockIdx.x * 256 + threadIdx.x) * 8;
  float4 a = *(const float4*)(x + i);
  float4 b = *(const float4*)(x + i + 4);
  int4 pk;
  pk.x = pk2(a.x, a.y); pk.y = pk2(a.z, a.w);
  pk.z = pk2(b.x, b.y); pk.w = pk2(b.z, b.w);
  *(int4*)(xb + i) = pk;
}

// Prep: cvt w_qkv [768][256] f32 -> bf16 (N x K), w_out [256][256] likewise,
// and gather the 64x64 relative-position bias table (f32).
__global__ void prep_kernel(const float* __restrict__ wq, const float* __restrict__ wo,
                            const float* __restrict__ pe, const int* __restrict__ rel,
                            bfu* __restrict__ wqB, bfu* __restrict__ woB,
                            float* __restrict__ bias)
{
  int t = blockIdx.x * 256 + threadIdx.x;
  if (t < 196608) wqB[t] = f2b(wq[t]);
  if (t < 65536)  woB[t] = f2b(wo[t]);
  if (t < 4096)   { int r0 = rel[2 * t], r1 = rel[2 * t + 1]; bias[t] = pe[r0 * 15 + r1]; }
}

// C[m][n] = sum_k A[m][k]*B[n][k] + bias[n].   M=131072, K=256, N=NBN*128.
// A: [M][256] bf16 row-major. B: [N][256] bf16 row-major.
// Staging: global_load_lds width=16, pre-swizzled global source (rule #21):
//   LDS[row][u_phys] = global[row][u_phys ^ (row&7)]; dest linear, lane-only swizzle.
// Double-buffered, 2-phase: issue next tile's loads before current MFMAs.
// MODE 0: scatter bf16 to windowed qkv layout (Q,K as [tok][c]; V transposed [c][tok]).
// MODE 1: dense f32 row-major out.
template<int NBN, int MODE>
__global__ __launch_bounds__(256)
void mfma_gemm(const bfu* __restrict__ A, const bfu* __restrict__ B,
               const float* __restrict__ bias, void* __restrict__ outv)
{
  __shared__ __align__(16) char lds[65536];   // [2 buf][A 16K | B 16K]
  const int t = threadIdx.x;
  const int lane = t & 63;
  const int l15 = lane & 15, l4 = lane >> 4;
  const int wid = t >> 6;
  const int wr = wid >> 1, wc = wid & 1;

  // XCD-chunked remap: consecutive work-ids (sharing an A panel) stay on one XCD's L2.
  const int L = blockIdx.x;
  const int chunk = (NBN * 1024) >> 3;
  const int w = (L & 7) * chunk + (L >> 3);
  const int bm = w / NBN, bn = w % NBN;

  // Per-lane fixed source pattern: row-in-group = lane>>3, unit = (lane&7)^(lane>>3).
  const int rg = lane >> 3;
  const int goff = rg * 256 + (((lane & 7) ^ rg) << 3);
  const bfu* Ab = A + (((size_t)(bm * 128)) << 8) + goff;
  const bfu* Bb = B + (((size_t)(bn * 128)) << 8) + goff;

  f32x4 acc[4][4] = {};

  auto STAGE = [&](int buf, int kt) {
    char* dst = lds + (buf << 15);
    const bfu* ga = Ab + (kt << 6);
    const bfu* gb = Bb + (kt << 6);
    #pragma unroll
    for (int r = 0; r < 4; ++r) {
      int rowg = (wid << 5) + (r << 3);          // 8-row group start
      gload_lds16(ga + (size_t)rowg * 256, dst + (rowg << 7));
      gload_lds16(gb + (size_t)rowg * 256, dst + 16384 + (rowg << 7));
    }
  };

  STAGE(0, 0);
  __syncthreads();

  for (int kt = 0; kt < 4; ++kt) {
    if (kt < 3) STAGE((kt + 1) & 1, kt + 1);
    const char* bufp = lds + ((kt & 1) << 15);

    #pragma unroll
    for (int kk = 0; kk < 2; ++kk) {
      bf16x8 af[4], bfr[4];
      #pragma unroll
      for (int ms = 0; ms < 4; ++ms) {
        int row = (wr << 6) + (ms << 4) + l15;
        int u = (((kk << 2) + l4) ^ (row & 7)) << 4;
        af[ms] = *(const bf16x8*)(bufp + (row << 7) + u);
      }
      #pragma unroll
      for (int ns = 0; ns < 4; ++ns) {
        int row = (wc << 6) + (ns << 4) + l15;
        int u = (((kk << 2) + l4) ^ (row & 7)) << 4;
        bfr[ns] = *(const bf16x8*)(bufp + 16384 + (row << 7) + u);
      }
      #pragma unroll
      for (int ms = 0; ms < 4; ++ms)
        #pragma unroll
        for (int ns = 0; ns < 4; ++ns)
          acc[ms][ns] = __builtin_amdgcn_mfma_f32_16x16x32_bf16(af[ms], bfr[ns], acc[ms][ns], 0, 0, 0);
    }
    __syncthreads();
  }

  // Epilogue. D[(l>>4)*4 + r][lane&15] = acc[..][r]  (HW-verified C/D mapping).
  if (MODE == 0) {
    bfu* out = (bfu*)outv;
    #pragma unroll
    for (int ns = 0; ns < 4; ++ns) {
      int n = bn * 128 + (wc << 6) + (ns << 4) + l15;
      float bb = bias[n];
      int mat = n >> 8, head = (n >> 5) & 7, cc = n & 31;
      #pragma unroll
      for (int ms = 0; ms < 4; ++ms) {
        int m = bm * 128 + (wr << 6) + (ms << 4) + (l4 << 2);
        int bl = m >> 14, y = (m >> 7) & 127, x = m & 127;
        int win = ((y >> 3) << 4) | (x >> 3);
        int tok = ((y & 7) << 3) | (x & 7);   // 4-aligned; r spans tok..tok+3
        if (mat == 2) {
          // V^T layout: [bl,win,head][c=32][tok=64], contiguous in tok.
          size_t tb = 2 * QKV_ELEMS + ((size_t)(bl * 256 + win) * 8 + head) * 2048
                    + (size_t)cc * 64 + tok;
          ushort4 u4;
          u4.x = f2b(acc[ms][ns][0] + bb);
          u4.y = f2b(acc[ms][ns][1] + bb);
          u4.z = f2b(acc[ms][ns][2] + bb);
          u4.w = f2b(acc[ms][ns][3] + bb);
          *(ushort4*)(out + tb) = u4;
        } else {
          size_t tb = (size_t)mat * QKV_ELEMS + ((size_t)(bl * 256 + win) * 8 + head) * 2048
                    + (size_t)tok * 32 + cc;
          #pragma unroll
          for (int r = 0; r < 4; ++r)
            out[tb + (size_t)r * 32] = f2b(acc[ms][ns][r] + bb);
        }
      }
    }
  } else {
    float* out = (float*)outv;
    #pragma unroll
    for (int ns = 0; ns < 4; ++ns) {
      int n = bn * 128 + (wc << 6) + (ns << 4) + l15;
      float bb = bias[n];
      #pragma unroll
      for (int ms = 0; ms < 4; ++ms) {
        int m = bm * 128 + (wr << 6) + (ms << 4) + (l4 << 2);
        #pragma unroll
        for (int r = 0; r < 4; ++r)
          out[((size_t)(m + r) << 8) + n] = acc[ms][ns][r] + bb;
      }
    }
  }
}

// MFMA window attention. One block per (bl, win); 4 waves x 2 heads each.
// Swapped QK^T (S^T = mfma(K, Q)) so each lane owns whole q-rows for softmax.
// P staged per-wave in XOR-swizzled LDS; V read pre-transposed from global.
__global__ __launch_bounds__(256)
void attn_mfma(const bfu* __restrict__ qkv, const float* __restrict__ bias,
               bfu* __restrict__ aout)
{
  __shared__ float bias_s[64 * 68];   // padded: stride 68 f32
  __shared__ bfu p_s[4][4096];        // per-wave swizzled [64][64] bf16
  __shared__ float inv_s[4][64];
  const int t = threadIdx.x;
  const int lane = t & 63, wid = t >> 6;
  const int l15 = lane & 15, l4 = lane >> 4;
  const int blwin = blockIdx.x;       // bl*256 + win
  const int bl = blwin >> 8, win = blwin & 255;

  {
    int idx = t << 4;
    int i = idx >> 6, j0 = idx & 63;
    #pragma unroll
    for (int e = 0; e < 4; ++e) {
      float4 v = *(const float4*)(bias + idx + e * 4);
      *(float4*)(bias_s + i * 68 + j0 + e * 4) = v;
    }
  }
  __syncthreads();

  char* ps = (char*)&p_s[wid][0];

  #pragma unroll 1
  for (int hh = 0; hh < 2; ++hh) {
    const int head = wid * 2 + hh;
    const bfu* qb  = qkv + ((size_t)blwin * 8 + head) * 2048;
    const bfu* kb  = qb + QKV_ELEMS;
    const bfu* vtb = qb + 2 * QKV_ELEMS;   // [32 c][64 tok]

    bf16x8 qf[4], kf[4], vf[2][2];
    #pragma unroll
    for (int i = 0; i < 4; ++i) {
      qf[i] = *(const bf16x8*)(qb + (i * 16 + l15) * 32 + l4 * 8);
      kf[i] = *(const bf16x8*)(kb + (i * 16 + l15) * 32 + l4 * 8);
    }
    #pragma unroll
    for (int nj = 0; nj < 2; ++nj)
      #pragma unroll
      for (int ks = 0; ks < 2; ++ks)
        vf[nj][ks] = *(const bf16x8*)(vtb + (nj * 16 + l15) * 64 + ks * 32 + l4 * 8);

    // S^T[j][i]: reg r -> j = mj*16 + l4*4 + r; col -> i = ni*16 + l15.
    f32x4 st[4][4] = {};   // [mj][ni]
    #pragma unroll
    for (int mj = 0; mj < 4; ++mj)
      #pragma unroll
      for (int ni = 0; ni < 4; ++ni)
        st[mj][ni] = __builtin_amdgcn_mfma_f32_16x16x32_bf16(kf[mj], qf[ni], st[mj][ni], 0, 0, 0);

    // scale + bias
    #pragma unroll
    for (int ni = 0; ni < 4; ++ni) {
      int i = ni * 16 + l15;
      #pragma unroll
      for (int mj = 0; mj < 4; ++mj) {
        float4 bb = *(const float4*)(bias_s + i * 68 + mj * 16 + l4 * 4);
        st[mj][ni][0] = fmaf(st[mj][ni][0], SCALE_F, bb.x);
        st[mj][ni][1] = fmaf(st[mj][ni][1], SCALE_F, bb.y);
        st[mj][ni][2] = fmaf(st[mj][ni][2], SCALE_F, bb.z);
        st[mj][ni][3] = fmaf(st[mj][ni][3], SCALE_F, bb.w);
      }
    }

    // softmax over j for each owned q-row; write unnormalized P to swizzled LDS.
    #pragma unroll
    for (int ni = 0; ni < 4; ++ni) {
      float mx = st[0][ni][0];
      #pragma unroll
      for (int mj = 0; mj < 4; ++mj)
        #pragma unroll
        for (int r = 0; r < 4; ++r)
          mx = fmaxf(mx, st[mj][ni][r]);
      mx = fmaxf(mx, __shfl_xor(mx, 16));
      mx = fmaxf(mx, __shfl_xor(mx, 32));
      float sum = 0.f;
      #pragma unroll
      for (int mj = 0; mj < 4; ++mj)
        #pragma unroll
        for (int r = 0; r < 4; ++r) {
          float p = __expf(st[mj][ni][r] - mx);
          st[mj][ni][r] = p;
          sum += p;
        }
      sum += __shfl_xor(sum, 16);
      sum += __shfl_xor(sum, 32);
      if (l4 == 0) inv_s[wid][ni * 16 + l15] = 1.0f / sum;
      const int i2 = ni * 16 + l15;
      const int swz = (i2 & 7) << 4;
      #pragma unroll
      for (int mj = 0; mj < 4; ++mj) {
        uint2 val;
        val.x = pk2(st[mj][ni][0], st[mj][ni][1]);
        val.y = pk2(st[mj][ni][2], st[mj][ni][3]);
        *(uint2*)(ps + i2 * 128 + ((mj * 32 + l4 * 8) ^ swz)) = val;
      }
    }

    // PV: O[i][c] = sum_j P[i][j] * Vt[c][j]
    f32x4 oacc[4][2] = {};
    #pragma unroll
    for (int mi = 0; mi < 4; ++mi) {
      int i = mi * 16 + l15;
      int swz = (i & 7) << 4;
      bf16x8 pf0 = *(const bf16x8*)(ps + i * 128 + ((l4 * 16) ^ swz));
      bf16x8 pf1 = *(const bf16x8*)(ps + i * 128 + ((64 + l4 * 16) ^ swz));
      #pragma unroll
      for (int nj = 0; nj < 2; ++nj) {
        oacc[mi][nj] = __builtin_amdgcn_mfma_f32_16x16x32_bf16(pf0, vf[nj][0], oacc[mi][nj], 0, 0, 0);
        oacc[mi][nj] = __builtin_amdgcn_mfma_f32_16x16x32_bf16(pf1, vf[nj][1], oacc[mi][nj], 0, 0, 0);
      }
    }

    // epilogue: row i = mi*16 + l4*4 + r, col c = nj*16 + l15
    #pragma unroll
    for (int mi = 0; mi < 4; ++mi) {
      #pragma unroll
      for (int r = 0; r < 4; ++r) {
        int tok = mi * 16 + (l4 << 2) + r;
        float inv = inv_s[wid][tok];
        int y = ((win >> 4) << 3) | (tok >> 3);
        int x = ((win & 15) << 3) | (tok & 7);
        size_t p = ((size_t)bl * 128 + y) * 128 + x;
        bfu* dst = aout + p * 256 + head * 32;
        #pragma unroll
        for (int nj = 0; nj < 2; ++nj)
          dst[nj * 16 + l15] = f2b(oacc[mi][nj][r] * inv);
      }
    }
  }
}

extern "C" void kernel_launch(void* const* d_in, const int* in_sizes, int n_in,
                              void* d_out, int out_size, void* d_ws, size_t ws_size,
                              hipStream_t stream)
{
  const float* x     = (const float*)d_in[0];
  const float* w_qkv = (const float*)d_in[1];
  const float* b_qkv = (const float*)d_in[2];
  const float* w_out = (const float*)d_in[3];
  const float* b_out = (const float*)d_in[4];
  const float* pe    = (const float*)d_in[5];
  const int*   rel   = (const int*)d_in[6];
  float* out = (float*)d_out;

  char* ws = (char*)d_ws;
  bfu*   qkv_ws  = (bfu*)(ws);                 // 3 * 33554432 bf16 = 192 MiB
  bfu*   attn_ws = (bfu*)(ws + 201326592);     // 33554432 bf16 = 64 MiB; ALSO xb (x as bf16)
  float* bias_ws = (float*)(ws + 268435456);   // 4096 f32
  bfu*   wqB     = (bfu*)(ws + 268451840);     // 196608 bf16 [768][256] (N x K)
  bfu*   woB     = (bfu*)(ws + 268845056);     // 65536 bf16 [256][256] (N x K)
  bfu*   xb      = attn_ws;                    // alias: dead before attn_mfma writes

  cvt_x<<<16384, 256, 0, stream>>>(x, xb);
  prep_kernel<<<768, 256, 0, stream>>>(w_qkv, w_out, pe, rel, wqB, woB, bias_ws);
  mfma_gemm<6, 0><<<6144, 256, 0, stream>>>(xb, wqB, b_qkv, qkv_ws);
  attn_mfma<<<2048, 256, 0, stream>>>(qkv_ws, bias_ws, attn_ws);
  mfma_gemm<2, 1><<<2048, 256, 0, stream>>>(attn_ws, woB, b_out, out);
}

// Round 8
// 253.151 us; speedup vs baseline: 4.8874x; 1.0350x over previous
//
#include <hip/hip_runtime.h>

// bf16 handled as raw ushort (bf16 = top 16 bits of fp32).
typedef unsigned short bfu;
typedef unsigned int u32;
typedef __attribute__((ext_vector_type(8))) short bf16x8;   // 8 bf16 = 4 VGPRs
typedef __attribute__((ext_vector_type(4))) float f32x4;

#define QKV_ELEMS 33554432ll   // per q/k/v matrix: 8 bl * 256 win * 8 head * 64 tok * 32 c
#define SCALE_F 0.17677669529663687f

__device__ __forceinline__ bfu f2b(float f) {
  unsigned int u = __float_as_uint(f);
  u += 0x7fffu + ((u >> 16) & 1u);   // round-to-nearest-even
  return (bfu)(u >> 16);
}
__device__ __forceinline__ unsigned pk2(float a, float b) {
  return ((unsigned)f2b(b) << 16) | (unsigned)f2b(a);
}
__device__ __forceinline__ void gload_lds16(const void* g, void* l) {
  __builtin_amdgcn_global_load_lds(
      (const __attribute__((address_space(1))) u32*)g,
      (__attribute__((address_space(3))) u32*)l, 16, 0, 0);
}

// x f32 [33554432] -> bf16 (round-to-nearest-even).
__global__ __launch_bounds__(256)
void cvt_x(const float* __restrict__ x, bfu* __restrict__ xb)
{
  size_t i = ((size_t)blockIdx.x * 256 + threadIdx.x) * 8;
  float4 a = *(const float4*)(x + i);
  float4 b = *(const float4*)(x + i + 4);
  int4 pk;
  pk.x = pk2(a.x, a.y); pk.y = pk2(a.z, a.w);
  pk.z = pk2(b.x, b.y); pk.w = pk2(b.z, b.w);
  *(int4*)(xb + i) = pk;
}

// Prep: cvt w_qkv [768][256] f32 -> bf16 (N x K), w_out [256][256] likewise,
// and gather the 64x64 relative-position bias table (f32).
__global__ void prep_kernel(const float* __restrict__ wq, const float* __restrict__ wo,
                            const float* __restrict__ pe, const int* __restrict__ rel,
                            bfu* __restrict__ wqB, bfu* __restrict__ woB,
                            float* __restrict__ bias)
{
  int t = blockIdx.x * 256 + threadIdx.x;
  if (t < 196608) wqB[t] = f2b(wq[t]);
  if (t < 65536)  woB[t] = f2b(wo[t]);
  if (t < 4096)   { int r0 = rel[2 * t], r1 = rel[2 * t + 1]; bias[t] = pe[r0 * 15 + r1]; }
}

// C[m][n] = sum_k A[m][k]*B[n][k] + bias[n].   M=131072, K=256.
// A: [M][256] bf16 row-major. B: [768|256][256] bf16 row-major (n = bn*128+..., bn += BNOFF).
// BK=32, double-buffered (2 x 16 KB LDS), safe schedule: STAGE(next) -> compute -> full barrier.
// Staging: global_load_lds w=16, pre-swizzled source (rule #21): LDS[row][u] = G[row][u ^ ((row>>1)&3)].
// MODE 0: Q/K scatter — SWAPPED mfma (C^T): reg r spans n -> ushort4 stores to [tok][c].
// MODE 2: V scatter — normal: reg r spans tok -> ushort4 stores to V^T [c][tok].
// MODE 1: dense f32 row-major out (normal orientation).
template<int NBN, int BNOFF, int MODE>
__global__ __launch_bounds__(256)
void mfma_gemm(const bfu* __restrict__ A, const bfu* __restrict__ B,
               const float* __restrict__ bias, void* __restrict__ outv)
{
  __shared__ __align__(16) char lds[32768];   // [2 buf][A 8K | B 8K]
  const int t = threadIdx.x;
  const int lane = t & 63;
  const int l15 = lane & 15, l4 = lane >> 4;
  const int wid = t >> 6;
  const int wr = wid >> 1, wc = wid & 1;

  // XCD-chunked remap: consecutive work-ids (sharing an A panel) stay on one XCD's L2.
  const int L = blockIdx.x;
  const int chunk = (NBN * 1024) >> 3;
  const int w = (L & 7) * chunk + (L >> 3);
  const int bm = w / NBN, bn = w % NBN + BNOFF;

  // Per-lane staging source: row-in-16 = lane>>2, src unit = (lane&3)^((lane>>3)&3).
  const int goff = (lane >> 2) * 256 + (((lane & 3) ^ ((lane >> 3) & 3)) << 3);
  const bfu* Ab = A + (((size_t)(bm * 128)) << 8) + goff;
  const bfu* Bb = B + (((size_t)(bn * 128)) << 8) + goff;

  f32x4 acc[4][4] = {};

  auto STAGE = [&](int buf, int kt) {
    char* dst = lds + (buf << 14);
    const bfu* ga = Ab + (kt << 5);
    const bfu* gb = Bb + (kt << 5);
    #pragma unroll
    for (int r = 0; r < 2; ++r) {
      int rowg = (wid << 5) + (r << 4);          // 16-row group start
      gload_lds16(ga + (size_t)rowg * 256, dst + (rowg << 6));
      gload_lds16(gb + (size_t)rowg * 256, dst + 8192 + (rowg << 6));
    }
  };

  STAGE(0, 0);
  __syncthreads();   // tile 0 landed (vmcnt(0) drain) + sync

  for (int kt = 0; kt < 8; ++kt) {
    if (kt < 7) STAGE((kt + 1) & 1, kt + 1);   // prefetch overlaps compute below
    const char* bufp = lds + ((kt & 1) << 14);

    bf16x8 af[4], bfr[4];
    #pragma unroll
    for (int ms = 0; ms < 4; ++ms) {
      int row = (wr << 6) + (ms << 4) + l15;
      int u = (l4 ^ ((row >> 1) & 3)) << 4;
      af[ms] = *(const bf16x8*)(bufp + (row << 6) + u);
    }
    #pragma unroll
    for (int ns = 0; ns < 4; ++ns) {
      int row = (wc << 6) + (ns << 4) + l15;
      int u = (l4 ^ ((row >> 1) & 3)) << 4;
      bfr[ns] = *(const bf16x8*)(bufp + 8192 + (row << 6) + u);
    }
    #pragma unroll
    for (int ms = 0; ms < 4; ++ms)
      #pragma unroll
      for (int ns = 0; ns < 4; ++ns) {
        if (MODE == 0)   // swapped: acc holds C^T tile (rows = n, cols = m)
          acc[ms][ns] = __builtin_amdgcn_mfma_f32_16x16x32_bf16(bfr[ns], af[ms], acc[ms][ns], 0, 0, 0);
        else
          acc[ms][ns] = __builtin_amdgcn_mfma_f32_16x16x32_bf16(af[ms], bfr[ns], acc[ms][ns], 0, 0, 0);
      }
    if (kt < 7) __syncthreads();   // reads of buf done (lgkmcnt) + next tile landed (vmcnt)
  }

  // Epilogues. C/D mapping: D[row = l4*4 + r][col = l15].
  if (MODE == 0) {
    // Q/K: C^T -> r spans n (4 consecutive channels), l15 spans tok.
    bfu* out = (bfu*)outv;
    #pragma unroll
    for (int ms = 0; ms < 4; ++ms) {
      int m = bm * 128 + (wr << 6) + (ms << 4) + l15;
      int bl = m >> 14, y = (m >> 7) & 127, x = m & 127;
      int win = ((y >> 3) << 4) | (x >> 3);
      int tok = ((y & 7) << 3) | (x & 7);
      size_t mbase = ((size_t)(bl * 256 + win) * 8) * 2048 + (size_t)tok * 32;
      #pragma unroll
      for (int ns = 0; ns < 4; ++ns) {
        int n0 = bn * 128 + (wc << 6) + (ns << 4) + (l4 << 2);   // 4-aligned, r spans n0..n0+3
        float4 bb = *(const float4*)(bias + n0);
        int mat = n0 >> 8, head = (n0 >> 5) & 7, cc = n0 & 31;
        ushort4 u4;
        u4.x = f2b(acc[ms][ns][0] + bb.x);
        u4.y = f2b(acc[ms][ns][1] + bb.y);
        u4.z = f2b(acc[ms][ns][2] + bb.z);
        u4.w = f2b(acc[ms][ns][3] + bb.w);
        *(ushort4*)(out + (size_t)mat * QKV_ELEMS + mbase + head * 2048 + cc) = u4;
      }
    }
  } else if (MODE == 2) {
    // V: normal -> r spans tok, l15 spans channel; store to V^T [c][tok].
    bfu* out = (bfu*)outv;
    #pragma unroll
    for (int ns = 0; ns < 4; ++ns) {
      int n = bn * 128 + (wc << 6) + (ns << 4) + l15;
      float bb = bias[n];
      int head = (n >> 5) & 7, cc = n & 31;
      #pragma unroll
      for (int ms = 0; ms < 4; ++ms) {
        int m = bm * 128 + (wr << 6) + (ms << 4) + (l4 << 2);
        int bl = m >> 14, y = (m >> 7) & 127, x = m & 127;
        int win = ((y >> 3) << 4) | (x >> 3);
        int tok = ((y & 7) << 3) | (x & 7);   // 4-aligned; r spans tok..tok+3
        size_t tb = 2 * QKV_ELEMS + ((size_t)(bl * 256 + win) * 8 + head) * 2048
                  + (size_t)cc * 64 + tok;
        ushort4 u4;
        u4.x = f2b(acc[ms][ns][0] + bb);
        u4.y = f2b(acc[ms][ns][1] + bb);
        u4.z = f2b(acc[ms][ns][2] + bb);
        u4.w = f2b(acc[ms][ns][3] + bb);
        *(ushort4*)(out + tb) = u4;
      }
    }
  } else {
    float* out = (float*)outv;
    #pragma unroll
    for (int ns = 0; ns < 4; ++ns) {
      int n = bn * 128 + (wc << 6) + (ns << 4) + l15;
      float bb = bias[n];
      #pragma unroll
      for (int ms = 0; ms < 4; ++ms) {
        int m = bm * 128 + (wr << 6) + (ms << 4) + (l4 << 2);
        #pragma unroll
        for (int r = 0; r < 4; ++r)
          out[((size_t)(m + r) << 8) + n] = acc[ms][ns][r] + bb;
      }
    }
  }
}

// MFMA window attention. One block per (bl, win); 4 waves x 2 heads each.
// Swapped QK^T (S^T = mfma(K, Q)) so each lane owns whole q-rows for softmax.
// P staged per-wave in XOR-swizzled LDS; V read pre-transposed from global.
__global__ __launch_bounds__(256)
void attn_mfma(const bfu* __restrict__ qkv, const float* __restrict__ bias,
               bfu* __restrict__ aout)
{
  __shared__ float bias_s[64 * 68];   // padded: stride 68 f32
  __shared__ bfu p_s[4][4096];        // per-wave swizzled [64][64] bf16
  __shared__ float inv_s[4][64];
  const int t = threadIdx.x;
  const int lane = t & 63, wid = t >> 6;
  const int l15 = lane & 15, l4 = lane >> 4;
  const int blwin = blockIdx.x;       // bl*256 + win
  const int bl = blwin >> 8, win = blwin & 255;

  {
    int idx = t << 4;
    int i = idx >> 6, j0 = idx & 63;
    #pragma unroll
    for (int e = 0; e < 4; ++e) {
      float4 v = *(const float4*)(bias + idx + e * 4);
      *(float4*)(bias_s + i * 68 + j0 + e * 4) = v;
    }
  }
  __syncthreads();

  char* ps = (char*)&p_s[wid][0];

  #pragma unroll 1
  for (int hh = 0; hh < 2; ++hh) {
    const int head = wid * 2 + hh;
    const bfu* qb  = qkv + ((size_t)blwin * 8 + head) * 2048;
    const bfu* kb  = qb + QKV_ELEMS;
    const bfu* vtb = qb + 2 * QKV_ELEMS;   // [32 c][64 tok]

    bf16x8 qf[4], kf[4], vf[2][2];
    #pragma unroll
    for (int i = 0; i < 4; ++i) {
      qf[i] = *(const bf16x8*)(qb + (i * 16 + l15) * 32 + l4 * 8);
      kf[i] = *(const bf16x8*)(kb + (i * 16 + l15) * 32 + l4 * 8);
    }
    #pragma unroll
    for (int nj = 0; nj < 2; ++nj)
      #pragma unroll
      for (int ks = 0; ks < 2; ++ks)
        vf[nj][ks] = *(const bf16x8*)(vtb + (nj * 16 + l15) * 64 + ks * 32 + l4 * 8);

    // S^T[j][i]: reg r -> j = mj*16 + l4*4 + r; col -> i = ni*16 + l15.
    f32x4 st[4][4] = {};   // [mj][ni]
    #pragma unroll
    for (int mj = 0; mj < 4; ++mj)
      #pragma unroll
      for (int ni = 0; ni < 4; ++ni)
        st[mj][ni] = __builtin_amdgcn_mfma_f32_16x16x32_bf16(kf[mj], qf[ni], st[mj][ni], 0, 0, 0);

    // scale + bias
    #pragma unroll
    for (int ni = 0; ni < 4; ++ni) {
      int i = ni * 16 + l15;
      #pragma unroll
      for (int mj = 0; mj < 4; ++mj) {
        float4 bb = *(const float4*)(bias_s + i * 68 + mj * 16 + l4 * 4);
        st[mj][ni][0] = fmaf(st[mj][ni][0], SCALE_F, bb.x);
        st[mj][ni][1] = fmaf(st[mj][ni][1], SCALE_F, bb.y);
        st[mj][ni][2] = fmaf(st[mj][ni][2], SCALE_F, bb.z);
        st[mj][ni][3] = fmaf(st[mj][ni][3], SCALE_F, bb.w);
      }
    }

    // softmax over j for each owned q-row; write unnormalized P to swizzled LDS.
    #pragma unroll
    for (int ni = 0; ni < 4; ++ni) {
      float mx = st[0][ni][0];
      #pragma unroll
      for (int mj = 0; mj < 4; ++mj)
        #pragma unroll
        for (int r = 0; r < 4; ++r)
          mx = fmaxf(mx, st[mj][ni][r]);
      mx = fmaxf(mx, __shfl_xor(mx, 16));
      mx = fmaxf(mx, __shfl_xor(mx, 32));
      float sum = 0.f;
      #pragma unroll
      for (int mj = 0; mj < 4; ++mj)
        #pragma unroll
        for (int r = 0; r < 4; ++r) {
          float p = __expf(st[mj][ni][r] - mx);
          st[mj][ni][r] = p;
          sum += p;
        }
      sum += __shfl_xor(sum, 16);
      sum += __shfl_xor(sum, 32);
      if (l4 == 0) inv_s[wid][ni * 16 + l15] = 1.0f / sum;
      const int i2 = ni * 16 + l15;
      const int swz = (i2 & 7) << 4;
      #pragma unroll
      for (int mj = 0; mj < 4; ++mj) {
        uint2 val;
        val.x = pk2(st[mj][ni][0], st[mj][ni][1]);
        val.y = pk2(st[mj][ni][2], st[mj][ni][3]);
        *(uint2*)(ps + i2 * 128 + ((mj * 32 + l4 * 8) ^ swz)) = val;
      }
    }

    // PV: O[i][c] = sum_j P[i][j] * Vt[c][j]
    f32x4 oacc[4][2] = {};
    #pragma unroll
    for (int mi = 0; mi < 4; ++mi) {
      int i = mi * 16 + l15;
      int swz = (i & 7) << 4;
      bf16x8 pf0 = *(const bf16x8*)(ps + i * 128 + ((l4 * 16) ^ swz));
      bf16x8 pf1 = *(const bf16x8*)(ps + i * 128 + ((64 + l4 * 16) ^ swz));
      #pragma unroll
      for (int nj = 0; nj < 2; ++nj) {
        oacc[mi][nj] = __builtin_amdgcn_mfma_f32_16x16x32_bf16(pf0, vf[nj][0], oacc[mi][nj], 0, 0, 0);
        oacc[mi][nj] = __builtin_amdgcn_mfma_f32_16x16x32_bf16(pf1, vf[nj][1], oacc[mi][nj], 0, 0, 0);
      }
    }

    // epilogue: row i = mi*16 + l4*4 + r, col c = nj*16 + l15
    #pragma unroll
    for (int mi = 0; mi < 4; ++mi) {
      #pragma unroll
      for (int r = 0; r < 4; ++r) {
        int tok = mi * 16 + (l4 << 2) + r;
        float inv = inv_s[wid][tok];
        int y = ((win >> 4) << 3) | (tok >> 3);
        int x = ((win & 15) << 3) | (tok & 7);
        size_t p = ((size_t)bl * 128 + y) * 128 + x;
        bfu* dst = aout + p * 256 + head * 32;
        #pragma unroll
        for (int nj = 0; nj < 2; ++nj)
          dst[nj * 16 + l15] = f2b(oacc[mi][nj][r] * inv);
      }
    }
  }
}

extern "C" void kernel_launch(void* const* d_in, const int* in_sizes, int n_in,
                              void* d_out, int out_size, void* d_ws, size_t ws_size,
                              hipStream_t stream)
{
  const float* x     = (const float*)d_in[0];
  const float* w_qkv = (const float*)d_in[1];
  const float* b_qkv = (const float*)d_in[2];
  const float* w_out = (const float*)d_in[3];
  const float* b_out = (const float*)d_in[4];
  const float* pe    = (const float*)d_in[5];
  const int*   rel   = (const int*)d_in[6];
  float* out = (float*)d_out;

  char* ws = (char*)d_ws;
  bfu*   qkv_ws  = (bfu*)(ws);                 // 3 * 33554432 bf16 = 192 MiB
  bfu*   attn_ws = (bfu*)(ws + 201326592);     // 33554432 bf16 = 64 MiB; ALSO xb (x as bf16)
  float* bias_ws = (float*)(ws + 268435456);   // 4096 f32
  bfu*   wqB     = (bfu*)(ws + 268451840);     // 196608 bf16 [768][256] (N x K)
  bfu*   woB     = (bfu*)(ws + 268845056);     // 65536 bf16 [256][256] (N x K)
  bfu*   xb      = attn_ws;                    // alias: dead before attn_mfma writes

  cvt_x<<<16384, 256, 0, stream>>>(x, xb);
  prep_kernel<<<768, 256, 0, stream>>>(w_qkv, w_out, pe, rel, wqB, woB, bias_ws);
  mfma_gemm<4, 0, 0><<<4096, 256, 0, stream>>>(xb, wqB, b_qkv, qkv_ws);   // Q,K (swapped C^T)
  mfma_gemm<2, 4, 2><<<2048, 256, 0, stream>>>(xb, wqB, b_qkv, qkv_ws);   // V -> V^T
  attn_mfma<<<2048, 256, 0, stream>>>(qkv_ws, bias_ws, attn_ws);
  mfma_gemm<2, 0, 1><<<2048, 256, 0, stream>>>(attn_ws, woB, b_out, out);
}

// Round 10
// 220.597 us; speedup vs baseline: 5.6087x; 1.1476x over previous
//
#include <hip/hip_runtime.h>

// bf16 handled as raw ushort (bf16 = top 16 bits of fp32).
typedef unsigned short bfu;
typedef unsigned int u32;
typedef __attribute__((ext_vector_type(8))) short bf16x8;   // 8 bf16 = 4 VGPRs
typedef __attribute__((ext_vector_type(4))) float f32x4;

#define QKV_ELEMS 33554432ll
#define SCALE_F 0.17677669529663687f

__device__ __forceinline__ bfu f2b(float f) {
  unsigned int u = __float_as_uint(f);
  u += 0x7fffu + ((u >> 16) & 1u);   // round-to-nearest-even
  return (bfu)(u >> 16);
}
__device__ __forceinline__ unsigned pk2(float a, float b) {
  return ((unsigned)f2b(b) << 16) | (unsigned)f2b(a);
}
__device__ __forceinline__ void gload_lds16(const void* g, void* l) {
  __builtin_amdgcn_global_load_lds(
      (const __attribute__((address_space(1))) u32*)g,
      (__attribute__((address_space(3))) u32*)l, 16, 0, 0);
}

// Prep: cvt w_qkv [768][256] f32 -> bf16 (N x K), w_out [256][256] likewise,
// and gather the 64x64 relative-position bias table (f32).
__global__ void prep_kernel(const float* __restrict__ wq, const float* __restrict__ wo,
                            const float* __restrict__ pe, const int* __restrict__ rel,
                            bfu* __restrict__ wqB, bfu* __restrict__ woB,
                            float* __restrict__ bias)
{
  int t = blockIdx.x * 256 + threadIdx.x;
  if (t < 196608) wqB[t] = f2b(wq[t]);
  if (t < 65536)  woB[t] = f2b(wo[t]);
  if (t < 4096)   { int r0 = rel[2 * t], r1 = rel[2 * t + 1]; bias[t] = pe[r0 * 15 + r1]; }
}

// Fused qkv-projection + window attention. One block per (bl, win), 512 thr,
// 8 waves; wave = head. Per-wave-private after a single __syncthreads.
// LDS: xwin [64 tok][256 c] bf16 unit-swizzled (32 KB) + per-wave
// {qs[64][40], ks[64][40] (stride 80 B), vs[32][72] (stride 144 B),
//  inv[64] f32, ps (8 KB, aliases qs+ks)} = 15104 B. Total 153600 B.
__global__ __launch_bounds__(512, 2)
void qkv_attn(const float* __restrict__ x, const bfu* __restrict__ wqB,
              const float* __restrict__ b_qkv, const float* __restrict__ bias,
              bfu* __restrict__ aout)
{
  __shared__ __align__(16) char slds[153600];
  const int t = threadIdx.x;
  const int lane = t & 63, wid = t >> 6;       // wid = head = staging y-row
  const int l15 = lane & 15, l4 = lane >> 4;
  const int blwin = blockIdx.x;
  const int bl = blwin >> 8, win = blwin & 255;

  // Stage x window: wave w stages y-row w (8 tokens x 256 ch) as bf16.
  // phys: slds[tok*512 + (u ^ (tok&15))*16 + sub], u = channel-unit (8 ch).
  {
    int y = ((win >> 4) << 3) | wid;
    size_t rowbase = (((size_t)bl * 16384) + (size_t)y * 128 + ((win & 15) << 3)) * 256;
    const float* px = x + rowbase + (lane << 2);
    #pragma unroll
    for (int i = 0; i < 8; ++i) {
      float4 v = *(const float4*)(px + i * 256);
      uint2 d; d.x = pk2(v.x, v.y); d.y = pk2(v.z, v.w);
      int tok = (wid << 3) | i;
      *(uint2*)(slds + tok * 512 + (((lane >> 1) ^ (tok & 15)) << 4) + ((lane & 1) << 3)) = d;
    }
  }
  __syncthreads();

  char* wbl = slds + 32768 + wid * 15104;
  char* qsB = wbl;
  char* ksB = wbl + 5120;
  char* vsB = wbl + 10240;
  float* invB = (float*)(wbl + 14848);
  char* psB = wbl;   // aliases qs/ks AFTER qf/kf frags are in registers
  const int h = wid;

  // ---- Q and K mini-GEMMs (swapped orientation: D[c][tok]) ----
  #pragma unroll 1
  for (int mat = 0; mat < 2; ++mat) {
    const bfu* wb = wqB + ((size_t)(mat * 256 + h * 32)) * 256;
    const float* bq = b_qkv + mat * 256 + h * 32;
    char* dstB = mat ? ksB : qsB;
    f32x4 acc[8] = {};
    #pragma unroll
    for (int kt = 0; kt < 8; ++kt) {
      bf16x8 xf[4];
      #pragma unroll
      for (int m = 0; m < 4; ++m) {
        int tok = (m << 4) + l15;
        int u = ((kt << 2) + l4) ^ (tok & 15);
        xf[m] = *(const bf16x8*)(slds + tok * 512 + (u << 4));
      }
      bf16x8 wf0 = *(const bf16x8*)(wb + (size_t)l15 * 256 + (kt << 5) + (l4 << 3));
      bf16x8 wf1 = *(const bf16x8*)(wb + (size_t)(16 + l15) * 256 + (kt << 5) + (l4 << 3));
      #pragma unroll
      for (int m = 0; m < 4; ++m) {
        acc[m]     = __builtin_amdgcn_mfma_f32_16x16x32_bf16(wf0, xf[m], acc[m], 0, 0, 0);
        acc[4 + m] = __builtin_amdgcn_mfma_f32_16x16x32_bf16(wf1, xf[m], acc[4 + m], 0, 0, 0);
      }
    }
    #pragma unroll
    for (int n = 0; n < 2; ++n) {
      int c0 = (n << 4) + (l4 << 2);
      float4 bb = *(const float4*)(bq + c0);
      #pragma unroll
      for (int m = 0; m < 4; ++m) {
        int tok = (m << 4) + l15;
        f32x4 a = acc[n * 4 + m];
        ushort4 u4;
        u4.x = f2b(a[0] + bb.x); u4.y = f2b(a[1] + bb.y);
        u4.z = f2b(a[2] + bb.z); u4.w = f2b(a[3] + bb.w);
        *(ushort4*)(dstB + tok * 80 + (c0 << 1)) = u4;
      }
    }
  }

  // ---- V mini-GEMM (normal orientation: D[tok][c]) -> vs [c][tok] ----
  {
    const bfu* wb = wqB + ((size_t)(512 + h * 32)) * 256;
    const float* bq = b_qkv + 512 + h * 32;
    f32x4 acc[8] = {};
    #pragma unroll
    for (int kt = 0; kt < 8; ++kt) {
      bf16x8 xf[4];
      #pragma unroll
      for (int m = 0; m < 4; ++m) {
        int tok = (m << 4) + l15;
        int u = ((kt << 2) + l4) ^ (tok & 15);
        xf[m] = *(const bf16x8*)(slds + tok * 512 + (u << 4));
      }
      bf16x8 wf0 = *(const bf16x8*)(wb + (size_t)l15 * 256 + (kt << 5) + (l4 << 3));
      bf16x8 wf1 = *(const bf16x8*)(wb + (size_t)(16 + l15) * 256 + (kt << 5) + (l4 << 3));
      #pragma unroll
      for (int m = 0; m < 4; ++m) {
        acc[m * 2]     = __builtin_amdgcn_mfma_f32_16x16x32_bf16(xf[m], wf0, acc[m * 2], 0, 0, 0);
        acc[m * 2 + 1] = __builtin_amdgcn_mfma_f32_16x16x32_bf16(xf[m], wf1, acc[m * 2 + 1], 0, 0, 0);
      }
    }
    #pragma unroll
    for (int m = 0; m < 4; ++m) {
      int tok0 = (m << 4) + (l4 << 2);
      #pragma unroll
      for (int n = 0; n < 2; ++n) {
        int c = (n << 4) + l15;
        float bbv = bq[c];
        f32x4 a = acc[m * 2 + n];
        ushort4 u4;
        u4.x = f2b(a[0] + bbv); u4.y = f2b(a[1] + bbv);
        u4.z = f2b(a[2] + bbv); u4.w = f2b(a[3] + bbv);
        *(ushort4*)(vsB + c * 144 + (tok0 << 1)) = u4;
      }
    }
  }

  // ---- attention (verified per-wave structure; frags from LDS) ----
  bf16x8 qf[4], kf[4];
  #pragma unroll
  for (int i = 0; i < 4; ++i) {
    qf[i] = *(const bf16x8*)(qsB + ((i << 4) + l15) * 80 + (l4 << 4));
    kf[i] = *(const bf16x8*)(ksB + ((i << 4) + l15) * 80 + (l4 << 4));
  }

  // S^T[j][i] = mfma(K, Q): reg r -> j = mj*16 + l4*4 + r; col i = ni*16 + l15.
  f32x4 st[4][4] = {};
  #pragma unroll
  for (int mj = 0; mj < 4; ++mj)
    #pragma unroll
    for (int ni = 0; ni < 4; ++ni)
      st[mj][ni] = __builtin_amdgcn_mfma_f32_16x16x32_bf16(kf[mj], qf[ni], st[mj][ni], 0, 0, 0);

  // scale + bias (bias table from global, L2-hot)
  #pragma unroll
  for (int ni = 0; ni < 4; ++ni) {
    int i = (ni << 4) + l15;
    #pragma unroll
    for (int mj = 0; mj < 4; ++mj) {
      float4 bb = *(const float4*)(bias + i * 64 + (mj << 4) + (l4 << 2));
      st[mj][ni][0] = fmaf(st[mj][ni][0], SCALE_F, bb.x);
      st[mj][ni][1] = fmaf(st[mj][ni][1], SCALE_F, bb.y);
      st[mj][ni][2] = fmaf(st[mj][ni][2], SCALE_F, bb.z);
      st[mj][ni][3] = fmaf(st[mj][ni][3], SCALE_F, bb.w);
    }
  }

  // qf/kf are in registers; ensure outstanding LDS reads retired before
  // overwriting their space with P (psB aliases qsB/ksB).
  asm volatile("s_waitcnt lgkmcnt(0)" ::: "memory");
  __builtin_amdgcn_sched_barrier(0);

  // softmax over j per owned q-row; unnormalized P -> swizzled psB.
  #pragma unroll
  for (int ni = 0; ni < 4; ++ni) {
    float mx = st[0][ni][0];
    #pragma unroll
    for (int mj = 0; mj < 4; ++mj)
      #pragma unroll
      for (int r = 0; r < 4; ++r)
        mx = fmaxf(mx, st[mj][ni][r]);
    mx = fmaxf(mx, __shfl_xor(mx, 16));
    mx = fmaxf(mx, __shfl_xor(mx, 32));
    float sum = 0.f;
    #pragma unroll
    for (int mj = 0; mj < 4; ++mj)
      #pragma unroll
      for (int r = 0; r < 4; ++r) {
        float p = __expf(st[mj][ni][r] - mx);
        st[mj][ni][r] = p;
        sum += p;
      }
    sum += __shfl_xor(sum, 16);
    sum += __shfl_xor(sum, 32);
    int i2 = (ni << 4) + l15;
    if (l4 == 0) invB[i2] = 1.0f / sum;
    const int swz = (i2 & 7) << 4;
    #pragma unroll
    for (int mj = 0; mj < 4; ++mj) {
      uint2 val;
      val.x = pk2(st[mj][ni][0], st[mj][ni][1]);
      val.y = pk2(st[mj][ni][2], st[mj][ni][3]);
      *(uint2*)(psB + i2 * 128 + (((mj << 5) + (l4 << 3)) ^ swz)) = val;
    }
  }

  // PV: O[i][c] = sum_j P[i][j] * Vt[c][j]
  bf16x8 vf[2][2];
  #pragma unroll
  for (int nj = 0; nj < 2; ++nj)
    #pragma unroll
    for (int ks = 0; ks < 2; ++ks)
      vf[nj][ks] = *(const bf16x8*)(vsB + ((nj << 4) + l15) * 144 + (ks << 6) + (l4 << 4));

  f32x4 oacc[4][2] = {};
  #pragma unroll
  for (int mi = 0; mi < 4; ++mi) {
    int i = (mi << 4) + l15;
    int swz = (i & 7) << 4;
    bf16x8 pf0 = *(const bf16x8*)(psB + i * 128 + ((l4 << 4) ^ swz));
    bf16x8 pf1 = *(const bf16x8*)(psB + i * 128 + ((64 + (l4 << 4)) ^ swz));
    #pragma unroll
    for (int nj = 0; nj < 2; ++nj) {
      oacc[mi][nj] = __builtin_amdgcn_mfma_f32_16x16x32_bf16(pf0, vf[nj][0], oacc[mi][nj], 0, 0, 0);
      oacc[mi][nj] = __builtin_amdgcn_mfma_f32_16x16x32_bf16(pf1, vf[nj][1], oacc[mi][nj], 0, 0, 0);
    }
  }

  // epilogue: row i = mi*16 + l4*4 + r, col c = nj*16 + l15
  #pragma unroll
  for (int mi = 0; mi < 4; ++mi) {
    #pragma unroll
    for (int r = 0; r < 4; ++r) {
      int tok = (mi << 4) + (l4 << 2) + r;
      float inv = invB[tok];
      int y = ((win >> 4) << 3) | (tok >> 3);
      int xp = ((win & 15) << 3) | (tok & 7);
      size_t p = ((size_t)bl * 128 + y) * 128 + xp;
      bfu* dst = aout + p * 256 + h * 32;
      #pragma unroll
      for (int nj = 0; nj < 2; ++nj)
        dst[(nj << 4) + l15] = f2b(oacc[mi][nj][r] * inv);
    }
  }
}

// Out-projection GEMM (round-8-verified): C[m][n] = sum_k A[m][k]*B[n][k] + bias[n].
// BK=32, double-buffered, STAGE(next) -> compute -> full barrier. f32 out.
template<int NBN>
__global__ __launch_bounds__(256)
void mfma_gemm(const bfu* __restrict__ A, const bfu* __restrict__ B,
               const float* __restrict__ bias, float* __restrict__ out)
{
  __shared__ __align__(16) char lds[32768];
  const int t = threadIdx.x;
  const int lane = t & 63;
  const int l15 = lane & 15, l4 = lane >> 4;
  const int wid = t >> 6;
  const int wr = wid >> 1, wc = wid & 1;

  const int L = blockIdx.x;
  const int chunk = (NBN * 1024) >> 3;
  const int w = (L & 7) * chunk + (L >> 3);
  const int bm = w / NBN, bn = w % NBN;

  const int goff = (lane >> 2) * 256 + (((lane & 3) ^ ((lane >> 3) & 3)) << 3);
  const bfu* Ab = A + (((size_t)(bm * 128)) << 8) + goff;
  const bfu* Bb = B + (((size_t)(bn * 128)) << 8) + goff;

  f32x4 acc[4][4] = {};

  auto STAGE = [&](int buf, int kt) {
    char* dst = lds + (buf << 14);
    const bfu* ga = Ab + (kt << 5);
    const bfu* gb = Bb + (kt << 5);
    #pragma unroll
    for (int r = 0; r < 2; ++r) {
      int rowg = (wid << 5) + (r << 4);
      gload_lds16(ga + (size_t)rowg * 256, dst + (rowg << 6));
      gload_lds16(gb + (size_t)rowg * 256, dst + 8192 + (rowg << 6));
    }
  };

  STAGE(0, 0);
  __syncthreads();

  for (int kt = 0; kt < 8; ++kt) {
    if (kt < 7) STAGE((kt + 1) & 1, kt + 1);
    const char* bufp = lds + ((kt & 1) << 14);

    bf16x8 af[4], bfr[4];
    #pragma unroll
    for (int ms = 0; ms < 4; ++ms) {
      int row = (wr << 6) + (ms << 4) + l15;
      int u = (l4 ^ ((row >> 1) & 3)) << 4;
      af[ms] = *(const bf16x8*)(bufp + (row << 6) + u);
    }
    #pragma unroll
    for (int ns = 0; ns < 4; ++ns) {
      int row = (wc << 6) + (ns << 4) + l15;
      int u = (l4 ^ ((row >> 1) & 3)) << 4;
      bfr[ns] = *(const bf16x8*)(bufp + 8192 + (row << 6) + u);
    }
    #pragma unroll
    for (int ms = 0; ms < 4; ++ms)
      #pragma unroll
      for (int ns = 0; ns < 4; ++ns)
        acc[ms][ns] = __builtin_amdgcn_mfma_f32_16x16x32_bf16(af[ms], bfr[ns], acc[ms][ns], 0, 0, 0);
    if (kt < 7) __syncthreads();
  }

  #pragma unroll
  for (int ns = 0; ns < 4; ++ns) {
    int n = bn * 128 + (wc << 6) + (ns << 4) + l15;
    float bb = bias[n];
    #pragma unroll
    for (int ms = 0; ms < 4; ++ms) {
      int m = bm * 128 + (wr << 6) + (ms << 4) + (l4 << 2);
      #pragma unroll
      for (int r = 0; r < 4; ++r)
        out[((size_t)(m + r) << 8) + n] = acc[ms][ns][r] + bb;
    }
  }
}

extern "C" void kernel_launch(void* const* d_in, const int* in_sizes, int n_in,
                              void* d_out, int out_size, void* d_ws, size_t ws_size,
                              hipStream_t stream)
{
  const float* x     = (const float*)d_in[0];
  const float* w_qkv = (const float*)d_in[1];
  const float* b_qkv = (const float*)d_in[2];
  const float* w_out = (const float*)d_in[3];
  const float* b_out = (const float*)d_in[4];
  const float* pe    = (const float*)d_in[5];
  const int*   rel   = (const int*)d_in[6];
  float* out = (float*)d_out;

  char* ws = (char*)d_ws;
  bfu*   attn_ws = (bfu*)(ws);                 // [131072][256] bf16 = 64 MiB
  float* bias_ws = (float*)(ws + 67108864);    // 4096 f32
  bfu*   wqB     = (bfu*)(ws + 67125248);      // 196608 bf16 [768][256]
  bfu*   woB     = (bfu*)(ws + 67518464);      // 65536 bf16 [256][256]

  prep_kernel<<<768, 256, 0, stream>>>(w_qkv, w_out, pe, rel, wqB, woB, bias_ws);
  qkv_attn<<<2048, 512, 0, stream>>>(x, wqB, b_qkv, bias_ws, attn_ws);
  mfma_gemm<2><<<2048, 256, 0, stream>>>(attn_ws, woB, b_out, out);
}